// Round 11
// baseline (193.985 us; speedup 1.0000x reference)
//
#include <hip/hip_runtime.h>

typedef _Float16 f16;
typedef _Float16 half8 __attribute__((ext_vector_type(8)));
typedef _Float16 half4v __attribute__((ext_vector_type(4)));
typedef __fp16 fp16x2 __attribute__((ext_vector_type(2)));
typedef float floatx4 __attribute__((ext_vector_type(4)));
typedef unsigned int uint;

constexpr int Bsz = 4, Tseq = 2048, Cdim = 1024, NH = 16, HDim = 64;
constexpr int Mtok = Bsz * Tseq;      // 8192
constexpr int NQT = Tseq / 64;        // 32 q-tiles
constexpr float QSCALE = 0.18033688f; // 0.125 * log2(e)

#define GLDS16(src, dst) __builtin_amdgcn_global_load_lds( \
    (const __attribute__((address_space(1))) void*)(src),  \
    (__attribute__((address_space(3))) void*)(dst), 16, 0, 0)

__device__ __forceinline__ float fexp2(float x) { return __builtin_amdgcn_exp2f(x); }
__device__ __forceinline__ uint pkrtz(float a, float b) {
  fp16x2 h = __builtin_amdgcn_cvt_pkrtz(a, b);
  return __builtin_bit_cast(uint, h);
}

// ---------------- f32 -> f16 conversion: weights only (x stays f32) ----------------
__global__ void cvt2_kernel(const float* __restrict__ wa, const float* __restrict__ wp,
                            f16* __restrict__ wah, f16* __restrict__ wph) {
  constexpr int nwa = 3 * Cdim * Cdim;
  int i = (blockIdx.x * blockDim.x + threadIdx.x) * 4;
  const float* src; f16* dst; int off;
  if (i < nwa) { src = wa; dst = wah; off = i; }
  else         { src = wp; dst = wph; off = i - nwa; }
  float4 v = *(const float4*)(src + off);
  half4v o;
  o[0] = (f16)v.x; o[1] = (f16)v.y; o[2] = (f16)v.z; o[3] = (f16)v.w;
  *(half4v*)(dst + off) = o;
}

// ---------------- GEMM body: C[m][n] = sum_k A[m][k] * B[n][k] ----------------
// R8 structure (single-buffer LDS, 2x __syncthreads per K-step — best measured).
// AF32/BF32: that operand is staged from global f32 via GLDS16 (4 floats/lane) into
// an f32 LDS tile (128 rows x 128B, 8 slots/row, XOR swizzle slot^(row&7) applied by
// pre-swizzling the GLOBAL source), converted to f16 at fragment-read time.
// EPI 0: q/k scatter [B,H,T,HD]. EPI 1: f32 row-major. EPI 2: swapped-operand V^T.
template<int EPI, int AF32, int BF32>
__device__ __forceinline__ void gemm_body(char* smem,
    const void* Aop, const void* Bop,
    float* __restrict__ outF,
    f16* __restrict__ q_out, f16* __restrict__ k_out, f16* __restrict__ v_out,
    int N, int K, int bid)
{
  constexpr int BK = 32;
  constexpr int BOFF = AF32 ? 16384 : 8192;  // B tile base (A is 16KB if f32 else 8KB)
  const int tid = threadIdx.x;
  const int wave = tid >> 6;
  const int lane = tid & 63;
  const int g = lane >> 4, lm = lane & 15;
  const int nbn = N / 128;
  const int bm = bid / nbn;
  const int bn = bid % nbn;
  const int m0 = bm * 128, n0 = bn * 128;
  const int wr = wave >> 1, wc = wave & 1;

  floatx4 acc[4][4];
#pragma unroll
  for (int i = 0; i < 4; ++i)
#pragma unroll
    for (int j = 0; j < 4; ++j) acc[i][j] = (floatx4)0.0f;

  for (int k0 = 0; k0 < K; k0 += BK) {
    __syncthreads();
    // ---- stage A ----
    if constexpr (AF32) {
      const float* Af = (const float*)Aop;
#pragma unroll
      for (int t = 0; t < 4; ++t) {
        int row = wave * 8 + (lane >> 3) + t * 32;
        int s = (lane & 7) ^ (row & 7);
        GLDS16(Af + (size_t)(m0 + row) * K + k0 + s * 4,
               smem + (wave * 8 + t * 32) * 128);
      }
    } else {
      const f16* Ah = (const f16*)Aop;
#pragma unroll
      for (int t = 0; t < 2; ++t) {
        int row = (wave * 2 + t) * 16 + (lane >> 2);
        int cg = (lane & 3) ^ ((row >> 1) & 3);
        GLDS16(Ah + (size_t)(m0 + row) * K + k0 + cg * 8,
               smem + (wave * 2 + t) * 1024);
      }
    }
    // ---- stage B ----
    if constexpr (BF32) {
      const float* Bf = (const float*)Bop;
#pragma unroll
      for (int t = 0; t < 4; ++t) {
        int row = wave * 8 + (lane >> 3) + t * 32;
        int s = (lane & 7) ^ (row & 7);
        GLDS16(Bf + (size_t)(n0 + row) * K + k0 + s * 4,
               smem + BOFF + (wave * 8 + t * 32) * 128);
      }
    } else {
      const f16* Bh = (const f16*)Bop;
#pragma unroll
      for (int t = 0; t < 2; ++t) {
        int row = (wave * 2 + t) * 16 + (lane >> 2);
        int cg = (lane & 3) ^ ((row >> 1) & 3);
        GLDS16(Bh + (size_t)(n0 + row) * K + k0 + cg * 8,
               smem + BOFF + (wave * 2 + t) * 1024);
      }
    }
    __syncthreads();

    half8 af[4], bf[4];
#pragma unroll
    for (int i = 0; i < 4; ++i) {
      int rowa = wr * 64 + i * 16 + lm;
      if constexpr (AF32) {
        float4 f0 = *(const float4*)(smem + rowa * 128 + 16 * ((2 * g)     ^ (rowa & 7)));
        float4 f1 = *(const float4*)(smem + rowa * 128 + 16 * ((2 * g + 1) ^ (rowa & 7)));
        half8 v;
        v[0] = (f16)f0.x; v[1] = (f16)f0.y; v[2] = (f16)f0.z; v[3] = (f16)f0.w;
        v[4] = (f16)f1.x; v[5] = (f16)f1.y; v[6] = (f16)f1.z; v[7] = (f16)f1.w;
        af[i] = v;
      } else {
        int cga = g ^ ((rowa >> 1) & 3);
        af[i] = *(const half8*)(smem + rowa * 64 + cga * 16);
      }
      int rowb = wc * 64 + i * 16 + lm;
      if constexpr (BF32) {
        float4 f0 = *(const float4*)(smem + BOFF + rowb * 128 + 16 * ((2 * g)     ^ (rowb & 7)));
        float4 f1 = *(const float4*)(smem + BOFF + rowb * 128 + 16 * ((2 * g + 1) ^ (rowb & 7)));
        half8 v;
        v[0] = (f16)f0.x; v[1] = (f16)f0.y; v[2] = (f16)f0.z; v[3] = (f16)f0.w;
        v[4] = (f16)f1.x; v[5] = (f16)f1.y; v[6] = (f16)f1.z; v[7] = (f16)f1.w;
        bf[i] = v;
      } else {
        int cgb = g ^ ((rowb >> 1) & 3);
        bf[i] = *(const half8*)(smem + BOFF + rowb * 64 + cgb * 16);
      }
    }
#pragma unroll
    for (int i = 0; i < 4; ++i)
#pragma unroll
      for (int j = 0; j < 4; ++j)
        acc[i][j] = __builtin_amdgcn_mfma_f32_16x16x32_f16(af[i], bf[j], acc[i][j], 0, 0, 0);
  }

#pragma unroll
  for (int i = 0; i < 4; ++i) {
#pragma unroll
    for (int j = 0; j < 4; ++j) {
#pragma unroll
      for (int r = 0; r < 4; ++r) {
        int m = m0 + wr * 64 + i * 16 + 4 * g + r;
        int n = n0 + wc * 64 + j * 16 + lm;
        float v = acc[i][j][r];
        if constexpr (EPI == 1) {
          outF[(size_t)m * N + n] = v;
        } else if constexpr (EPI == 0) {
          int which = n >> 10;
          int inner = n & 1023;
          int h = inner >> 6, hd = inner & 63;
          int b = m >> 11, t = m & 2047;
          if (which == 0) {
            v *= QSCALE;  // fold softmax scale*log2e into Q
            q_out[(((size_t)(b * NH + h)) * Tseq + t) * HDim + hd] = (f16)v;
          } else {
            k_out[(((size_t)(b * NH + h)) * Tseq + t) * HDim + hd] = (f16)v;
          }
        } else {
          // swapped-operand V^T: m = W_v row (h*64+hd), n = token; lane-contiguous t
          int h = m >> 6, hd = m & 63;
          int b = n >> 11, t = n & 2047;
          v_out[(((size_t)(b * NH + h)) * HDim + hd) * Tseq + t] = (f16)v;
        }
      }
    }
  }
}

// qk projection (sbid 0..1023, A = x f32, B = W_qk f16)
// + V^T projection (sbid 1024..1535, A = W_v f16, B = x f32), XCD-swizzled
__global__ __launch_bounds__(256)
void qkv_kernel(const float* __restrict__ x, const f16* __restrict__ wAh,
                f16* __restrict__ Qh, f16* __restrict__ Kh, f16* __restrict__ Vth) {
  __shared__ __align__(16) char smem[24576];
  int sbid = (blockIdx.x & 7) * 192 + (blockIdx.x >> 3);  // 1536 = 8*192, bijective
  if (sbid < 1024)
    gemm_body<0, 1, 0>(smem, x, wAh, nullptr, Qh, Kh, nullptr, 2048, Cdim, sbid);
  else
    gemm_body<2, 0, 1>(smem, wAh + (size_t)2048 * Cdim, x, nullptr, nullptr, nullptr, Vth,
                       Mtok, Cdim, sbid - 1024);
}

__global__ __launch_bounds__(256)
void proj_kernel(const f16* __restrict__ yh, const f16* __restrict__ wPh, float* __restrict__ out) {
  __shared__ __align__(16) char smem[16384];
  int sbid = (blockIdx.x & 7) * 64 + (blockIdx.x >> 3);   // 512 = 8*64, bijective
  gemm_body<1, 0, 0>(smem, yh, wPh, out, nullptr, nullptr, nullptr, Cdim, Cdim, sbid);
}

// ---------------- causal flash attention: sequential paired q-tiles ----------------
// Every block runs EXACTLY 33 uniform iterations: phase B = q-tile 31-p over kv tiles
// 0..31-p, then phase A = q-tile p over kv tiles 0..p. acc/qf registers reused across
// phases. Divide-only softmax (p = 2^s, no running max — see R7 notes).
__device__ __forceinline__ void softmax_tile(floatx4* s, float& l_run,
                                             bool diag, int j0, int qg, char* pwrow, int g, int lm) {
  if (diag) {
#pragma unroll
    for (int nf = 0; nf < 4; ++nf)
#pragma unroll
      for (int r = 0; r < 4; ++r)
        if (j0 + nf * 16 + 4 * g + r > qg) s[nf][r] = -1e30f;
  }
  float rs = 0.f;
#pragma unroll
  for (int nf = 0; nf < 4; ++nf) {
    float p0 = fexp2(s[nf][0]), p1 = fexp2(s[nf][1]);
    float p2 = fexp2(s[nf][2]), p3 = fexp2(s[nf][3]);
    rs += (p0 + p1) + (p2 + p3);
    uint lo = pkrtz(p0, p1), hi = pkrtz(p2, p3);
    int slot = 2 * nf + (g >> 1);
    uint2 u; u.x = lo; u.y = hi;
    *(uint2*)(pwrow + 16 * (slot ^ (lm & 7)) + 8 * (g & 1)) = u;
  }
  l_run += rs;
}

__device__ __forceinline__ void store_o(const floatx4* acc, float l, int q0w, int g, int lm,
                                        f16* __restrict__ Y, int b, int h) {
  l += __shfl_xor(l, 16, 64);   // cross-lane l reduction, once per q-tile
  l += __shfl_xor(l, 32, 64);
#pragma unroll
  for (int r = 0; r < 4; ++r) {
    float lq = __shfl(l, 4 * g + r, 64);
    float inv = 1.0f / lq;
    int t = q0w + 4 * g + r;
    size_t base = ((size_t)(b * Tseq + t)) * Cdim + h * HDim;
#pragma unroll
    for (int ng = 0; ng < 4; ++ng)
      Y[base + ng * 16 + lm] = (f16)(acc[ng][r] * inv);
  }
}

__global__ __launch_bounds__(256)
void attn_kernel(const f16* __restrict__ Q, const f16* __restrict__ Kg,
                 const f16* __restrict__ Vt, f16* __restrict__ Y)
{
  // LDS: K dbuf 2*8192 @0 | V^T dbuf 2*8192 @16384 | P 4 waves * 2048 @32768 == 40960
  __shared__ __align__(16) char smem[40960];
  int wg = blockIdx.x;
  int lin = (wg & 7) * 128 + (wg >> 3);   // XCD-locality remap
  const int p  = lin & 15;
  const int bh = lin >> 4;
  const int itB = NQT - p;                // iterations in phase B (q-tile 31-p)
  const f16* Qb  = Q  + (size_t)bh * Tseq * HDim;
  const f16* Kb  = Kg + (size_t)bh * Tseq * HDim;
  const f16* Vtb = Vt + (size_t)bh * HDim * Tseq;   // [hd][t]

  const int tid = threadIdx.x, w = tid >> 6, lane = tid & 63;
  const int g = lane >> 4, lm = lane & 15;
  char* pwrow = smem + 32768 + w * 2048 + lm * 128;
  const int b = bh >> 4, h = bh & 15;

  // phase B state
  int q0 = (NQT - 1 - p) * 64;
  int qg = q0 + w * 16 + lm;
  half8 qf0 = *(const half8*)(Qb + (size_t)(q0 + w * 16 + lm) * HDim + g * 8);
  half8 qf1 = *(const half8*)(Qb + (size_t)(q0 + w * 16 + lm) * HDim + 32 + g * 8);

  floatx4 acc[4];
  float l = 0.f;
#pragma unroll
  for (int ng = 0; ng < 4; ++ng) acc[ng] = (floatx4)0.f;

  // staging: per GLDS instr a wave covers 8 rows (128B each); LDS dest linear,
  // bank-XOR swizzle achieved by pre-swizzling the GLOBAL source colgroup.
  const int srow = w * 8 + (lane >> 3);
  const int sslot = lane & 7;

  auto stage = [&](int j0s, int buf) {
#pragma unroll
    for (int t = 0; t < 2; ++t) {
      int row = srow + t * 32;
      int cg = sslot ^ (row & 7);
      GLDS16(Kb + (size_t)(j0s + row) * HDim + cg * 8,
             smem + buf * 8192 + (w * 8 + t * 32) * 128);
      GLDS16(Vtb + (size_t)row * Tseq + j0s + cg * 8,
             smem + 16384 + buf * 8192 + (w * 8 + t * 32) * 128);
    }
  };

  stage(0, 0);  // prologue: tile 0 -> buf 0

  for (int it = 0; it < NQT + 1; ++it) {
    const bool lastB = (it == itB - 1);
    const bool last  = (it == NQT);
    const int jt = (it < itB) ? it : it - itB;
    const int j0 = jt * 64;

    if (!last) {
      const int itn = it + 1;
      const int jtn = (itn < itB) ? itn : itn - itB;
      stage(jtn * 64, itn & 1);                        // next tile in flight
      asm volatile("s_waitcnt vmcnt(4)" ::: "memory"); // this tile's 4 GLDS done
    } else {
      asm volatile("s_waitcnt vmcnt(0)" ::: "memory");
    }
    __builtin_amdgcn_s_barrier();                      // tile it visible to all waves

    char* kb   = smem + (it & 1) * 8192;
    char* vbuf = smem + 16384 + (it & 1) * 8192;

    floatx4 s[4];
    __builtin_amdgcn_s_setprio(1);
#pragma unroll
    for (int nf = 0; nf < 4; ++nf) {
      half8 kf0 = *(const half8*)(kb + (nf * 16 + lm) * 128 + 16 * ((g)     ^ (lm & 7)));
      half8 kf1 = *(const half8*)(kb + (nf * 16 + lm) * 128 + 16 * ((4 + g) ^ (lm & 7)));
      s[nf] = __builtin_amdgcn_mfma_f32_16x16x32_f16(kf0, qf0, (floatx4)0.f, 0, 0, 0);
      s[nf] = __builtin_amdgcn_mfma_f32_16x16x32_f16(kf1, qf1, s[nf], 0, 0, 0);
    }
    __builtin_amdgcn_s_setprio(0);

    softmax_tile(s, l, lastB || last, j0, qg, pwrow, g, lm);
    half8 pa0 = *(const half8*)(pwrow + 16 * ((g)     ^ (lm & 7)));
    half8 pa1 = *(const half8*)(pwrow + 16 * ((4 + g) ^ (lm & 7)));

    __builtin_amdgcn_s_setprio(1);
#pragma unroll
    for (int c = 0; c < 2; ++c)
#pragma unroll
      for (int ng = 0; ng < 4; ++ng) {
        half8 vbf = *(const half8*)(vbuf + (ng * 16 + lm) * 128 + 16 * ((4 * c + g) ^ (lm & 7)));
        acc[ng] = __builtin_amdgcn_mfma_f32_16x16x32_f16(c ? pa1 : pa0, vbf, acc[ng], 0, 0, 0);
      }
    __builtin_amdgcn_s_setprio(0);

    __builtin_amdgcn_s_barrier();   // all waves done reading buf[it&1]

    if (lastB) {
      // phase B complete: store O_B, switch registers to phase A (q-tile p)
      store_o(acc, l, q0 + 16 * w, g, lm, Y, b, h);
      q0 = p * 64;
      qg = q0 + w * 16 + lm;
      qf0 = *(const half8*)(Qb + (size_t)(q0 + w * 16 + lm) * HDim + g * 8);
      qf1 = *(const half8*)(Qb + (size_t)(q0 + w * 16 + lm) * HDim + 32 + g * 8);
      l = 0.f;
#pragma unroll
      for (int ng = 0; ng < 4; ++ng) acc[ng] = (floatx4)0.f;
    }
  }

  store_o(acc, l, q0 + 16 * w, g, lm, Y, b, h);
}

// ---------------- launcher ----------------
extern "C" void kernel_launch(void* const* d_in, const int* in_sizes, int n_in,
                              void* d_out, int out_size, void* d_ws, size_t ws_size,
                              hipStream_t stream)
{
  const float* x      = (const float*)d_in[0];
  const float* W_attn = (const float*)d_in[1];
  const float* W_proj = (const float*)d_in[2];
  float* out = (float*)d_out;

  char* ws = (char*)d_ws;
  f16* wAh = (f16*)(ws);                         // 6 MB
  f16* wPh = (f16*)(ws + (size_t)(6u << 20));    // 2 MB
  f16* Qh  = (f16*)(ws + (size_t)(8u << 20));    // 16 MB
  f16* Kh  = (f16*)(ws + (size_t)(24u << 20));   // 16 MB
  f16* Vth = (f16*)(ws + (size_t)(40u << 20));   // 16 MB, V^T [B,H,HD,T]
  f16* yh  = (f16*)(ws + (size_t)(56u << 20));   // 16 MB

  constexpr int ntot = (3 * Cdim * Cdim + Cdim * Cdim) / 4;  // 1048576
  cvt2_kernel<<<ntot / 256, 256, 0, stream>>>(W_attn, W_proj, wAh, wPh);

  qkv_kernel<<<dim3(1536), 256, 0, stream>>>(x, wAh, Qh, Kh, Vth);

  attn_kernel<<<dim3(1024), 256, 0, stream>>>(Qh, Kh, Vth, yh);

  proj_kernel<<<dim3(512), 256, 0, stream>>>(yh, wPh, out);
}

// Round 12
// 172.852 us; speedup vs baseline: 1.1223x; 1.1223x over previous
//
#include <hip/hip_runtime.h>

typedef _Float16 f16;
typedef _Float16 half8 __attribute__((ext_vector_type(8)));
typedef _Float16 half4v __attribute__((ext_vector_type(4)));
typedef __fp16 fp16x2 __attribute__((ext_vector_type(2)));
typedef float floatx4 __attribute__((ext_vector_type(4)));
typedef unsigned int uint;

constexpr int Bsz = 4, Tseq = 2048, Cdim = 1024, NH = 16, HDim = 64;
constexpr int Mtok = Bsz * Tseq;      // 8192
constexpr int NQT = Tseq / 64;        // 32 q-tiles
constexpr float QSCALE = 0.18033688f; // 0.125 * log2(e)

#define GLDS16(src, dst) __builtin_amdgcn_global_load_lds( \
    (const __attribute__((address_space(1))) void*)(src),  \
    (__attribute__((address_space(3))) void*)(dst), 16, 0, 0)

__device__ __forceinline__ float fexp2(float x) { return __builtin_amdgcn_exp2f(x); }
__device__ __forceinline__ uint pkrtz(float a, float b) {
  fp16x2 h = __builtin_amdgcn_cvt_pkrtz(a, b);
  return __builtin_bit_cast(uint, h);
}

// ---------------- fused f32 -> f16 conversion (x, W_attn, W_proj) ----------------
__global__ void cvt3_kernel(const float* __restrict__ x, const float* __restrict__ wa,
                            const float* __restrict__ wp,
                            f16* __restrict__ xh, f16* __restrict__ wah, f16* __restrict__ wph) {
  constexpr int nx = Mtok * Cdim, nwa = 3 * Cdim * Cdim, nwp = Cdim * Cdim;
  int i = (blockIdx.x * blockDim.x + threadIdx.x) * 4;
  const float* src; f16* dst; int off;
  if (i < nx)            { src = x;  dst = xh;  off = i; }
  else if (i < nx + nwa) { src = wa; dst = wah; off = i - nx; }
  else                   { src = wp; dst = wph; off = i - nx - nwa; }
  float4 v = *(const float4*)(src + off);
  half4v o;
  o[0] = (f16)v.x; o[1] = (f16)v.y; o[2] = (f16)v.z; o[3] = (f16)v.w;
  *(half4v*)(dst + off) = o;
}

// ---------------- GEMM body: C[m][n] = sum_k A[m][k] * B[n][k] ----------------
// R8 structure verbatim: single-buffer LDS, 2x __syncthreads per K-step (best measured;
// dbuf/f32-staging/operand-swap all regressed — occupancy & L2 locality dominate here).
// EPI 0: q/k scatter [B,H,T,HD]. EPI 1: f32 row-major. EPI 2: swapped-operand V^T.
template<int EPI>
__device__ __forceinline__ void gemm_body(f16* As, f16* Bs,
    const f16* __restrict__ X, const f16* __restrict__ W,
    float* __restrict__ outF,
    f16* __restrict__ q_out, f16* __restrict__ k_out, f16* __restrict__ v_out,
    int N, int K, int bid)
{
  constexpr int BK = 32;
  const int tid = threadIdx.x;
  const int wave = tid >> 6;
  const int lane = tid & 63;
  const int g = lane >> 4, lm = lane & 15;
  const int nbn = N / 128;
  const int bm = bid / nbn;
  const int bn = bid % nbn;
  const int m0 = bm * 128, n0 = bn * 128;
  const int wr = wave >> 1, wc = wave & 1;

  floatx4 acc[4][4];
#pragma unroll
  for (int i = 0; i < 4; ++i)
#pragma unroll
    for (int j = 0; j < 4; ++j) acc[i][j] = (floatx4)0.0f;

  for (int k0 = 0; k0 < K; k0 += BK) {
    __syncthreads();
#pragma unroll
    for (int t = 0; t < 2; ++t) {
      int row = (wave * 2 + t) * 16 + (lane >> 2);
      int cg = (lane & 3) ^ ((row >> 1) & 3);   // pre-swizzled global source
      GLDS16(X + (size_t)(m0 + row) * K + k0 + cg * 8,
             (char*)As + (wave * 2 + t) * 1024);
      GLDS16(W + (size_t)(n0 + row) * K + k0 + cg * 8,
             (char*)Bs + (wave * 2 + t) * 1024);
    }
    __syncthreads();

    half8 af[4], bf[4];
#pragma unroll
    for (int i = 0; i < 4; ++i) {
      int rowa = wr * 64 + i * 16 + lm;
      int cga = g ^ ((rowa >> 1) & 3);
      af[i] = *(const half8*)((const char*)As + rowa * 64 + cga * 16);
      int rowb = wc * 64 + i * 16 + lm;
      int cgb = g ^ ((rowb >> 1) & 3);
      bf[i] = *(const half8*)((const char*)Bs + rowb * 64 + cgb * 16);
    }
#pragma unroll
    for (int i = 0; i < 4; ++i)
#pragma unroll
      for (int j = 0; j < 4; ++j)
        acc[i][j] = __builtin_amdgcn_mfma_f32_16x16x32_f16(af[i], bf[j], acc[i][j], 0, 0, 0);
  }

#pragma unroll
  for (int i = 0; i < 4; ++i) {
#pragma unroll
    for (int j = 0; j < 4; ++j) {
#pragma unroll
      for (int r = 0; r < 4; ++r) {
        int m = m0 + wr * 64 + i * 16 + 4 * g + r;
        int n = n0 + wc * 64 + j * 16 + lm;
        float v = acc[i][j][r];
        if constexpr (EPI == 1) {
          outF[(size_t)m * N + n] = v;
        } else if constexpr (EPI == 0) {
          int which = n >> 10;
          int inner = n & 1023;
          int h = inner >> 6, hd = inner & 63;
          int b = m >> 11, t = m & 2047;
          if (which == 0) {
            v *= QSCALE;  // fold softmax scale*log2e into Q
            q_out[(((size_t)(b * NH + h)) * Tseq + t) * HDim + hd] = (f16)v;
          } else {
            k_out[(((size_t)(b * NH + h)) * Tseq + t) * HDim + hd] = (f16)v;
          }
        } else {
          // swapped-operand V^T: m = W_v row (h*64+hd), n = token; lane-contiguous t
          int h = m >> 6, hd = m & 63;
          int b = n >> 11, t = n & 2047;
          v_out[(((size_t)(b * NH + h)) * HDim + hd) * Tseq + t] = (f16)v;
        }
      }
    }
  }
}

// qk projection (sbid 0..1023) + V^T projection (sbid 1024..1535), XCD-swizzled
__global__ __launch_bounds__(256)
void qkv_kernel(const f16* __restrict__ xh, const f16* __restrict__ wAh,
                f16* __restrict__ Qh, f16* __restrict__ Kh, f16* __restrict__ Vth) {
  __shared__ __align__(16) f16 As[128 * 32];
  __shared__ __align__(16) f16 Bs[128 * 32];
  int sbid = (blockIdx.x & 7) * 192 + (blockIdx.x >> 3);  // 1536 = 8*192, bijective
  if (sbid < 1024)
    gemm_body<0>(As, Bs, xh, wAh, nullptr, Qh, Kh, nullptr, 2048, Cdim, sbid);
  else
    gemm_body<2>(As, Bs, wAh + (size_t)2048 * Cdim, xh, nullptr, nullptr, nullptr, Vth,
                 Mtok, Cdim, sbid - 1024);
}

__global__ __launch_bounds__(256)
void proj_kernel(const f16* __restrict__ yh, const f16* __restrict__ wPh, float* __restrict__ out) {
  __shared__ __align__(16) f16 As[128 * 32];
  __shared__ __align__(16) f16 Bs[128 * 32];
  int sbid = (blockIdx.x & 7) * 64 + (blockIdx.x >> 3);   // 512 = 8*64, bijective
  gemm_body<1>(As, Bs, yh, wPh, out, nullptr, nullptr, nullptr, Cdim, Cdim, sbid);
}

// ---------------- causal flash attention: sequential paired q-tiles ----------------
// Every block runs EXACTLY 33 uniform iterations: phase B = q-tile 31-p over kv tiles
// 0..31-p, then phase A = q-tile p over kv tiles 0..p. acc/qf registers reused across
// phases. Divide-only softmax (p = 2^s, no running max — see R7 notes).
// ONE barrier per iteration: {stage next -> compute current -> vmcnt(0) -> barrier}.
// Race audit: stage at iter i writes buf[(i+1)&1], last READ in iter i-1 and protected
// by the end-of-(i-1) barrier; per-wave vmcnt(0) before the barrier guarantees staged
// data is complete before any wave enters iter i+1.
__device__ __forceinline__ void softmax_tile(floatx4* s, float& l_run,
                                             bool diag, int j0, int qg, char* pwrow, int g, int lm) {
  if (diag) {
#pragma unroll
    for (int nf = 0; nf < 4; ++nf)
#pragma unroll
      for (int r = 0; r < 4; ++r)
        if (j0 + nf * 16 + 4 * g + r > qg) s[nf][r] = -1e30f;
  }
  float rs = 0.f;
#pragma unroll
  for (int nf = 0; nf < 4; ++nf) {
    float p0 = fexp2(s[nf][0]), p1 = fexp2(s[nf][1]);
    float p2 = fexp2(s[nf][2]), p3 = fexp2(s[nf][3]);
    rs += (p0 + p1) + (p2 + p3);
    uint lo = pkrtz(p0, p1), hi = pkrtz(p2, p3);
    int slot = 2 * nf + (g >> 1);
    uint2 u; u.x = lo; u.y = hi;
    *(uint2*)(pwrow + 16 * (slot ^ (lm & 7)) + 8 * (g & 1)) = u;
  }
  l_run += rs;
}

__device__ __forceinline__ void store_o(const floatx4* acc, float l, int q0w, int g, int lm,
                                        f16* __restrict__ Y, int b, int h) {
  l += __shfl_xor(l, 16, 64);   // cross-lane l reduction, once per q-tile
  l += __shfl_xor(l, 32, 64);
#pragma unroll
  for (int r = 0; r < 4; ++r) {
    float lq = __shfl(l, 4 * g + r, 64);
    float inv = 1.0f / lq;
    int t = q0w + 4 * g + r;
    size_t base = ((size_t)(b * Tseq + t)) * Cdim + h * HDim;
#pragma unroll
    for (int ng = 0; ng < 4; ++ng)
      Y[base + ng * 16 + lm] = (f16)(acc[ng][r] * inv);
  }
}

__global__ __launch_bounds__(256)
void attn_kernel(const f16* __restrict__ Q, const f16* __restrict__ Kg,
                 const f16* __restrict__ Vt, f16* __restrict__ Y)
{
  // LDS: K dbuf 2*8192 @0 | V^T dbuf 2*8192 @16384 | P 4 waves * 2048 @32768 == 40960
  __shared__ __align__(16) char smem[40960];
  int wg = blockIdx.x;
  int lin = (wg & 7) * 128 + (wg >> 3);   // XCD-locality remap
  const int p  = lin & 15;
  const int bh = lin >> 4;
  const int itB = NQT - p;                // iterations in phase B (q-tile 31-p)
  const f16* Qb  = Q  + (size_t)bh * Tseq * HDim;
  const f16* Kb  = Kg + (size_t)bh * Tseq * HDim;
  const f16* Vtb = Vt + (size_t)bh * HDim * Tseq;   // [hd][t]

  const int tid = threadIdx.x, w = tid >> 6, lane = tid & 63;
  const int g = lane >> 4, lm = lane & 15;
  char* pwrow = smem + 32768 + w * 2048 + lm * 128;
  const int b = bh >> 4, h = bh & 15;

  // phase B state
  int q0 = (NQT - 1 - p) * 64;
  int qg = q0 + w * 16 + lm;
  half8 qf0 = *(const half8*)(Qb + (size_t)(q0 + w * 16 + lm) * HDim + g * 8);
  half8 qf1 = *(const half8*)(Qb + (size_t)(q0 + w * 16 + lm) * HDim + 32 + g * 8);

  floatx4 acc[4];
  float l = 0.f;
#pragma unroll
  for (int ng = 0; ng < 4; ++ng) acc[ng] = (floatx4)0.f;

  // staging: per GLDS instr a wave covers 8 rows (128B each); LDS dest linear,
  // bank-XOR swizzle achieved by pre-swizzling the GLOBAL source colgroup.
  const int srow = w * 8 + (lane >> 3);
  const int sslot = lane & 7;

  auto stage = [&](int j0s, int buf) {
#pragma unroll
    for (int t = 0; t < 2; ++t) {
      int row = srow + t * 32;
      int cg = sslot ^ (row & 7);
      GLDS16(Kb + (size_t)(j0s + row) * HDim + cg * 8,
             smem + buf * 8192 + (w * 8 + t * 32) * 128);
      GLDS16(Vtb + (size_t)row * Tseq + j0s + cg * 8,
             smem + 16384 + buf * 8192 + (w * 8 + t * 32) * 128);
    }
  };

  // prologue: stage tile 0, make it visible
  stage(0, 0);
  asm volatile("s_waitcnt vmcnt(0)" ::: "memory");
  __builtin_amdgcn_s_barrier();

  for (int it = 0; it < NQT + 1; ++it) {
    const bool lastB = (it == itB - 1);
    const bool last  = (it == NQT);
    const int jt = (it < itB) ? it : it - itB;
    const int j0 = jt * 64;

    if (!last) {   // issue next tile's stage; latency hides under this iter's compute
      const int itn = it + 1;
      const int jtn = (itn < itB) ? itn : itn - itB;
      stage(jtn * 64, itn & 1);
    }

    char* kb   = smem + (it & 1) * 8192;
    char* vbuf = smem + 16384 + (it & 1) * 8192;

    floatx4 s[4];
    __builtin_amdgcn_s_setprio(1);
#pragma unroll
    for (int nf = 0; nf < 4; ++nf) {
      half8 kf0 = *(const half8*)(kb + (nf * 16 + lm) * 128 + 16 * ((g)     ^ (lm & 7)));
      half8 kf1 = *(const half8*)(kb + (nf * 16 + lm) * 128 + 16 * ((4 + g) ^ (lm & 7)));
      s[nf] = __builtin_amdgcn_mfma_f32_16x16x32_f16(kf0, qf0, (floatx4)0.f, 0, 0, 0);
      s[nf] = __builtin_amdgcn_mfma_f32_16x16x32_f16(kf1, qf1, s[nf], 0, 0, 0);
    }
    __builtin_amdgcn_s_setprio(0);

    softmax_tile(s, l, lastB || last, j0, qg, pwrow, g, lm);
    half8 pa0 = *(const half8*)(pwrow + 16 * ((g)     ^ (lm & 7)));
    half8 pa1 = *(const half8*)(pwrow + 16 * ((4 + g) ^ (lm & 7)));

    __builtin_amdgcn_s_setprio(1);
#pragma unroll
    for (int c = 0; c < 2; ++c)
#pragma unroll
      for (int ng = 0; ng < 4; ++ng) {
        half8 vbf = *(const half8*)(vbuf + (ng * 16 + lm) * 128 + 16 * ((4 * c + g) ^ (lm & 7)));
        acc[ng] = __builtin_amdgcn_mfma_f32_16x16x32_f16(c ? pa1 : pa0, vbf, acc[ng], 0, 0, 0);
      }
    __builtin_amdgcn_s_setprio(0);

    // single sync point: my stage loads drained, everyone's reads of buf[it&1] done
    asm volatile("s_waitcnt vmcnt(0)" ::: "memory");
    __builtin_amdgcn_s_barrier();

    if (lastB) {
      // phase B complete: store O_B, switch registers to phase A (q-tile p)
      store_o(acc, l, q0 + 16 * w, g, lm, Y, b, h);
      q0 = p * 64;
      qg = q0 + w * 16 + lm;
      qf0 = *(const half8*)(Qb + (size_t)(q0 + w * 16 + lm) * HDim + g * 8);
      qf1 = *(const half8*)(Qb + (size_t)(q0 + w * 16 + lm) * HDim + 32 + g * 8);
      l = 0.f;
#pragma unroll
      for (int ng = 0; ng < 4; ++ng) acc[ng] = (floatx4)0.f;
    }
  }

  store_o(acc, l, q0 + 16 * w, g, lm, Y, b, h);
}

// ---------------- launcher ----------------
extern "C" void kernel_launch(void* const* d_in, const int* in_sizes, int n_in,
                              void* d_out, int out_size, void* d_ws, size_t ws_size,
                              hipStream_t stream)
{
  const float* x      = (const float*)d_in[0];
  const float* W_attn = (const float*)d_in[1];
  const float* W_proj = (const float*)d_in[2];
  float* out = (float*)d_out;

  char* ws = (char*)d_ws;
  f16* xh  = (f16*)(ws);
  f16* wAh = (f16*)(ws + (size_t)(16u << 20));
  f16* wPh = (f16*)(ws + (size_t)(22u << 20));
  f16* Qh  = (f16*)(ws + (size_t)(24u << 20));
  f16* Kh  = (f16*)(ws + (size_t)(40u << 20));
  f16* Vth = (f16*)(ws + (size_t)(56u << 20));  // V^T [B,H,HD,T]
  f16* yh  = xh;

  constexpr int ntot = (Mtok * Cdim + 3 * Cdim * Cdim + Cdim * Cdim) / 4;
  cvt3_kernel<<<(ntot + 255) / 256, 256, 0, stream>>>(x, W_attn, W_proj, xh, wAh, wPh);

  qkv_kernel<<<dim3(1536), 256, 0, stream>>>(xh, wAh, Qh, Kh, Vth);

  attn_kernel<<<dim3(1024), 256, 0, stream>>>(Qh, Kh, Vth, yh);

  proj_kernel<<<dim3(512), 256, 0, stream>>>(yh, wPh, out);
}